// Round 8
// baseline (57.733 us; speedup 1.0000x reference)
//
#include <hip/hip_runtime.h>

#define Bq 32
#define Sq 8
#define Lq 128
#define Dq 768
#define Aq 10
#define Tq 8

typedef float f32x4 __attribute__((ext_vector_type(4)));

constexpr int D4   = Dq / 4;     // 192 float4 columns
constexpr int NBS  = Bq * Sq;    // 256
constexpr int NBSA = NBS * Aq;   // 2560
constexpr int NJ   = 3 * Aq;     // 30 (set,a) pairs

// One wave per block; block = (bs, D-third). The wave:
//  1. ballot-selects chosen token + row-match bitmask for all 30 (set,a)
//  2. streams its 64-float4 column slice of emb[bs] ONCE (NT loads),
//     accumulating pool in registers and matched-arg sums in LDS
//  3. writes pool + 30 arg outputs (NT stores; nothing is ever re-read)
// Arg gathers never touch global memory -> pure single-pass stream.
__global__ __launch_bounds__(64) void srl_fused_k(
    const int* __restrict__ sids, const float* __restrict__ mask,
    const float* __restrict__ emb, const int* __restrict__ pred,
    const int* __restrict__ a0, const int* __restrict__ a1,
    float* __restrict__ out)
{
    int bid  = blockIdx.x;
    int lane = threadIdx.x;          // 0..63
    int bs    = bid / 3;
    int third = bid - bs * 3;

    __shared__ f32x4        accA[NJ][64];   // 30 KB arg accumulators
    __shared__ float        marr[Lq];
    __shared__ unsigned int mbits[Lq];      // per-row 30-bit match mask
    __shared__ float        scl[NJ];        // per-(set,a) 1/count (0 if none)

    // zero arg accumulators
#pragma unroll
    for (int j = 0; j < NJ; ++j) accA[j][lane] = (f32x4){0.f, 0.f, 0.f, 0.f};

    // mask row + count (wave butterfly)
    float m0 = mask[(size_t)bs * Lq + lane];
    float m1 = mask[(size_t)bs * Lq + 64 + lane];
    marr[lane]      = m0;
    marr[64 + lane] = m1;
    float mv = m0 + m1;
    for (int off = 32; off > 0; off >>= 1) mv += __shfl_xor(mv, off);
    float invm = 1.0f / fmaxf(mv, 1.0f);     // clip(count, 1, None)

    // sentence in 2 regs/lane
    int s0 = sids[(size_t)bs * Lq + lane];
    int s1 = sids[(size_t)bs * Lq + 64 + lane];

    // ---- ballot selection for all 30 (set,a); build row bitmasks ---------
    unsigned int mb0 = 0, mb1 = 0;
#pragma unroll
    for (int set = 0; set < 3; ++set) {
        const int* ids = (set == 0) ? pred : ((set == 1) ? a0 : a1);
        for (int a = 0; a < Aq; ++a) {
            int bsa = bs * Aq + a;
            int idv = (lane < Tq) ? ids[(size_t)bsa * Tq + lane] : 0;

            unsigned long long B0 = 0, B1 = 0;
            int cc = 0;
#pragma unroll
            for (int t = Tq - 1; t >= 0; --t) {
                if (cc == 0) {                       // wave-uniform
                    int idt = __shfl(idv, t);
                    if (idt != 0) {
                        unsigned long long b0 = __ballot(s0 == idt);
                        unsigned long long b1 = __ballot(s1 == idt);
                        int c = (int)(__popcll(b0) + __popcll(b1));
                        if (c > 0) { B0 = b0; B1 = b1; cc = c; }
                    }
                }
            }
            int j = set * Aq + a;
            mb0 |= (unsigned int)((B0 >> lane) & 1ull) << j;
            mb1 |= (unsigned int)((B1 >> lane) & 1ull) << j;
            if (lane == 0) scl[j] = (cc > 0) ? 1.0f / (float)cc : 0.0f;
        }
    }
    mbits[lane]      = mb0;
    mbits[64 + lane] = mb1;
    __syncthreads();    // single wave: compiles to waitcnt

    // ---- single pass over 128 rows ---------------------------------------
    const f32x4* eb = (const f32x4*)emb +
                      (size_t)bs * Lq * D4 + third * 64 + lane;
    f32x4 accP = {0.f, 0.f, 0.f, 0.f};
#pragma unroll 8
    for (int l = 0; l < Lq; ++l) {
        f32x4 v = __builtin_nontemporal_load(&eb[(size_t)l * D4]);
        accP += v * marr[l];                 // LDS broadcast
        unsigned int mb = mbits[l];          // wave-uniform
        while (mb) {                         // rare (~0.23 events/row)
            int j = (int)__builtin_ctz(mb); mb &= mb - 1;
            accA[j][lane] += v;              // LDS RMW, per-lane slot
        }
    }

    // ---- outputs (all NT: never re-read) ----------------------------------
    __builtin_nontemporal_store(accP * invm,
        (f32x4*)out + (size_t)bs * D4 + third * 64 + lane);

#pragma unroll
    for (int j = 0; j < NJ; ++j) {
        int set = j / Aq, a = j - set * Aq;
        int bsa = bs * Aq + a;
        f32x4 r = accA[j][lane] * scl[j];
        __builtin_nontemporal_store(r,
            (f32x4*)out + ((size_t)NBS + (size_t)set * NBSA + bsa) * D4 +
            third * 64 + lane);
    }
}

extern "C" void kernel_launch(void* const* d_in, const int* in_sizes, int n_in,
                              void* d_out, int out_size, void* d_ws, size_t ws_size,
                              hipStream_t stream) {
    const int*   sids = (const int*)d_in[0];
    const float* mask = (const float*)d_in[1];
    const float* emb  = (const float*)d_in[2];
    const int*   pred = (const int*)d_in[3];
    const int*   a0   = (const int*)d_in[4];
    const int*   a1   = (const int*)d_in[5];
    float* out = (float*)d_out;

    srl_fused_k<<<NBS * 3, 64, 0, stream>>>(sids, mask, emb,
                                            pred, a0, a1, out);
}

// Round 9
// 50.606 us; speedup vs baseline: 1.1408x; 1.1408x over previous
//
#include <hip/hip_runtime.h>

#define Bq 32
#define Sq 8
#define Lq 128
#define Dq 768
#define Aq 10
#define Tq 8

typedef float f32x4 __attribute__((ext_vector_type(4)));

constexpr int D4   = Dq / 4;     // 192 float4 columns
constexpr int NBS  = Bq * Sq;    // 256
constexpr int NBSA = NBS * Aq;   // 2560
constexpr int NJ   = 3 * Aq;     // 30 (set,a) pairs

// One wave per block; block = (bs, D-third).
//  phase 0: ballots for all 30 (set,a) -> (B0,B1,scale) in 600B LDS
//  phase 1: branchless pool stream of 128 rows x 64 f32x4 (pipelined)
//  phase 2: per-(set,a) gathers re-read rows THIS wave just streamed
//           (warm L1/L2 on this CU; worst case = cold, bounded by R3)
// NT stores only (outputs never re-read); normal loads (gathers need L2).
__global__ __launch_bounds__(64) void srl_fused_k(
    const int* __restrict__ sids, const float* __restrict__ mask,
    const float* __restrict__ emb, const int* __restrict__ pred,
    const int* __restrict__ a0, const int* __restrict__ a1,
    float* __restrict__ out)
{
    int bid   = blockIdx.x;
    int lane  = threadIdx.x;         // 0..63
    int bs    = bid / 3;
    int third = bid - bs * 3;

    __shared__ unsigned long long sB0[NJ], sB1[NJ];
    __shared__ float sscl[NJ];
    __shared__ float marr[Lq];

    // mask row + count (wave butterfly)
    float m0 = mask[(size_t)bs * Lq + lane];
    float m1 = mask[(size_t)bs * Lq + 64 + lane];
    marr[lane]      = m0;
    marr[64 + lane] = m1;
    float mv = m0 + m1;
    for (int off = 32; off > 0; off >>= 1) mv += __shfl_xor(mv, off);
    float invm = 1.0f / fmaxf(mv, 1.0f);      // clip(count, 1, None)

    // sentence in 2 regs/lane
    int s0 = sids[(size_t)bs * Lq + lane];
    int s1 = sids[(size_t)bs * Lq + 64 + lane];

    // ---- phase 0: ballot selection for all 30 (set,a) --------------------
#pragma unroll
    for (int set = 0; set < 3; ++set) {
        const int* ids = (set == 0) ? pred : ((set == 1) ? a0 : a1);
        for (int a = 0; a < Aq; ++a) {
            int bsa = bs * Aq + a;
            int idv = (lane < Tq) ? ids[(size_t)bsa * Tq + lane] : 0;

            unsigned long long B0 = 0, B1 = 0;
            int cc = 0;
#pragma unroll
            for (int t = Tq - 1; t >= 0; --t) {
                if (cc == 0) {                       // wave-uniform select
                    int idt = __shfl(idv, t);
                    if (idt != 0) {
                        unsigned long long b0 = __ballot(s0 == idt);
                        unsigned long long b1 = __ballot(s1 == idt);
                        int c = (int)(__popcll(b0) + __popcll(b1));
                        if (c > 0) { B0 = b0; B1 = b1; cc = c; }
                    }
                }
            }
            int j = set * Aq + a;
            if (lane == 0) {
                sB0[j] = B0; sB1[j] = B1;
                sscl[j] = (cc > 0) ? 1.0f / (float)cc : 0.0f;
            }
        }
    }
    __syncthreads();   // single wave: compiles to a waitcnt

    // ---- phase 1: pure pool stream (branchless, pipelined) ---------------
    const f32x4* eb = (const f32x4*)emb +
                      (size_t)bs * Lq * D4 + third * 64 + lane;
    f32x4 accP = {0.f, 0.f, 0.f, 0.f};
#pragma unroll 16
    for (int l = 0; l < Lq; ++l) {
        f32x4 v = eb[(size_t)l * D4];        // normal load: seed L1/L2
        accP += v * marr[l];                 // LDS broadcast
    }
    __builtin_nontemporal_store(accP * invm,
        (f32x4*)out + (size_t)bs * D4 + third * 64 + lane);

    // ---- phase 2: gathers from just-streamed (warm) lines -----------------
#pragma unroll 2
    for (int j = 0; j < NJ; ++j) {
        unsigned long long B0 = sB0[j], B1 = sB1[j];   // LDS broadcast
        float scl = sscl[j];

        f32x4 acc = {0.f, 0.f, 0.f, 0.f};
        while (B0) {                 // ascending l: deterministic order
            int l = (int)__builtin_ctzll(B0); B0 &= B0 - 1;
            acc += eb[(size_t)l * D4];
        }
        while (B1) {
            int l = (int)__builtin_ctzll(B1) + 64; B1 &= B1 - 1;
            acc += eb[(size_t)l * D4];
        }

        int set = j / Aq, a = j - (j / Aq) * Aq;
        int bsa = bs * Aq + a;
        __builtin_nontemporal_store(acc * scl,
            (f32x4*)out + ((size_t)NBS + (size_t)set * NBSA + bsa) * D4 +
            third * 64 + lane);
    }
}

extern "C" void kernel_launch(void* const* d_in, const int* in_sizes, int n_in,
                              void* d_out, int out_size, void* d_ws, size_t ws_size,
                              hipStream_t stream) {
    const int*   sids = (const int*)d_in[0];
    const float* mask = (const float*)d_in[1];
    const float* emb  = (const float*)d_in[2];
    const int*   pred = (const int*)d_in[3];
    const int*   a0   = (const int*)d_in[4];
    const int*   a1   = (const int*)d_in[5];
    float* out = (float*)d_out;

    srl_fused_k<<<NBS * 3, 64, 0, stream>>>(sids, mask, emb,
                                            pred, a0, a1, out);
}

// Round 10
// 34.618 us; speedup vs baseline: 1.6677x; 1.4619x over previous
//
#include <hip/hip_runtime.h>

#define Bq 32
#define Sq 8
#define Lq 128
#define Dq 768
#define Aq 10
#define Tq 8

typedef float f32x4 __attribute__((ext_vector_type(4)));

constexpr int D4   = Dq / 4;     // 192 float4 columns
constexpr int NBS  = Bq * Sq;    // 256
constexpr int NBSA = NBS * Aq;   // 2560

// ---------------- kernel A: pure mean-pool stream -------------------------
// 256 blocks x 192 threads. Each block streams its (b,s) 393KB contiguous
// slab with NO other traffic in the machine. NT store (out never re-read).
__global__ __launch_bounds__(192) void pool_k(
    const float* __restrict__ mask, const float* __restrict__ emb,
    float* __restrict__ out)
{
    int bs  = blockIdx.x;
    int tid = threadIdx.x;

    __shared__ float marr[Lq];
    __shared__ float msum;

    if (tid < Lq) marr[tid] = mask[(size_t)bs * Lq + tid];
    if (tid < 64) {
        float mv = mask[(size_t)bs * Lq + tid] +
                   mask[(size_t)bs * Lq + 64 + tid];
        for (int off = 32; off > 0; off >>= 1)
            mv += __shfl_xor(mv, off);
        if (tid == 0) msum = mv;
    }
    __syncthreads();

    const f32x4* eb = (const f32x4*)emb + (size_t)bs * Lq * D4 + tid;
    f32x4 acc = {0.f, 0.f, 0.f, 0.f};
#pragma unroll 16
    for (int l = 0; l < Lq; ++l) {
        float m = marr[l];                   // LDS broadcast
        f32x4 v = eb[(size_t)l * D4];        // contiguous 3KB/row per block
        acc += v * m;
    }
    float inv = 1.0f / fmaxf(msum, 1.0f);    // clip(count, 1, None)
    f32x4 r = acc * inv;
    __builtin_nontemporal_store(r, (f32x4*)out + (size_t)bs * D4 + tid);
}

// ---------------- kernel B: arg embeddings (runs after the stream) --------
// 256 blocks x 192 threads; wave = set; loop a = 0..9. Gathers re-read emb
// rows that kernel A just pulled through L2/L3 -> mostly cache hits.
__global__ __launch_bounds__(192) void arg_k(
    const int* __restrict__ sids, const float* __restrict__ emb,
    const int* __restrict__ pred, const int* __restrict__ a0,
    const int* __restrict__ a1, float* __restrict__ out)
{
    int bs   = blockIdx.x;
    int tid  = threadIdx.x;
    int set  = tid >> 6;               // 0:pred 1:arg0 2:arg1
    int lane = tid & 63;
    const int* ids = (set == 0) ? pred : ((set == 1) ? a0 : a1);

    int s0 = sids[(size_t)bs * Lq + lane];
    int s1 = sids[(size_t)bs * Lq + 64 + lane];

    const f32x4* eb = (const f32x4*)emb + (size_t)bs * Lq * D4;

    for (int a = 0; a < Aq; ++a) {
        int bsa = bs * Aq + a;
        int idv = (lane < Tq) ? ids[(size_t)bsa * Tq + lane] : 0;

        // last t (descending) whose nonzero id occurs in the sentence
        unsigned long long B0 = 0, B1 = 0;
        int ccount = 0;
#pragma unroll
        for (int t = Tq - 1; t >= 0; --t) {
            if (ccount == 0) {                       // wave-uniform
                int idt = __shfl(idv, t);
                if (idt != 0) {
                    unsigned long long b0 = __ballot(s0 == idt);
                    unsigned long long b1 = __ballot(s1 == idt);
                    int c = (int)(__popcll(b0) + __popcll(b1));
                    if (c > 0) { B0 = b0; B1 = b1; ccount = c; }
                }
            }
        }

        // gather matched rows (uniform bit loops, ascending l: deterministic)
        f32x4 acc0 = {0.f, 0.f, 0.f, 0.f};
        f32x4 acc1 = acc0, acc2 = acc0;
        unsigned long long b = B0;
        while (b) {
            int l = (int)__builtin_ctzll(b); b &= b - 1;
            acc0 += eb[(size_t)l * D4 + lane];
            acc1 += eb[(size_t)l * D4 + 64 + lane];
            acc2 += eb[(size_t)l * D4 + 128 + lane];
        }
        b = B1;
        while (b) {
            int l = (int)__builtin_ctzll(b) + 64; b &= b - 1;
            acc0 += eb[(size_t)l * D4 + lane];
            acc1 += eb[(size_t)l * D4 + 64 + lane];
            acc2 += eb[(size_t)l * D4 + 128 + lane];
        }

        float inv = (ccount > 0) ? 1.0f / (float)ccount : 0.0f;
        f32x4* o4 = (f32x4*)out +
                    ((size_t)NBS + (size_t)set * NBSA + bsa) * D4;
        __builtin_nontemporal_store(acc0 * inv, o4 + lane);
        __builtin_nontemporal_store(acc1 * inv, o4 + 64 + lane);
        __builtin_nontemporal_store(acc2 * inv, o4 + 128 + lane);
    }
}

extern "C" void kernel_launch(void* const* d_in, const int* in_sizes, int n_in,
                              void* d_out, int out_size, void* d_ws, size_t ws_size,
                              hipStream_t stream) {
    const int*   sids = (const int*)d_in[0];
    const float* mask = (const float*)d_in[1];
    const float* emb  = (const float*)d_in[2];
    const int*   pred = (const int*)d_in[3];
    const int*   a0   = (const int*)d_in[4];
    const int*   a1   = (const int*)d_in[5];
    float* out = (float*)d_out;

    pool_k<<<NBS, 192, 0, stream>>>(mask, emb, out);
    arg_k<<<NBS, 192, 0, stream>>>(sids, emb, pred, a0, a1, out);
}

// Round 11
// 25.418 us; speedup vs baseline: 2.2713x; 1.3619x over previous
//
#include <hip/hip_runtime.h>

#define Bq 32
#define Sq 8
#define Lq 128
#define Dq 768
#define Aq 10
#define Tq 8

typedef float f32x4 __attribute__((ext_vector_type(4)));

constexpr int D4    = Dq / 4;       // 192 float4 columns
constexpr int NBS   = Bq * Sq;      // 256
constexpr int NBSA  = NBS * Aq;     // 2560
constexpr int NPOOL = NBS;          // 256 pool blocks (one per b,s)
constexpr int NARG  = NBS;          // 256 arg blocks (one per b,s; wave=set)

// R3 structure (best: 25.96us) + non-temporal STORES only.
// Loads stay normal: arg gathers re-hit the L2 lines the pool stream of the
// same (b,s) pulled in on the same XCD (bid and 256+bid map to the same XCD).
// NT stores keep the 24MB of never-re-read output from evicting those lines.
__global__ __launch_bounds__(192) void srl_fused_k(
    const int* __restrict__ sids, const float* __restrict__ mask,
    const float* __restrict__ emb, const int* __restrict__ pred,
    const int* __restrict__ a0, const int* __restrict__ a1,
    float* __restrict__ out)
{
    int bid = blockIdx.x;
    int tid = threadIdx.x;

    if (bid < NPOOL) {
        // ---- mean pool: block = (b,s); thread = float4 column; 128 rows --
        int bs = bid;
        __shared__ float marr[Lq];
        __shared__ float msum;

        if (tid < 64) {
            float m0 = mask[(size_t)bs * Lq + tid];
            float m1 = mask[(size_t)bs * Lq + 64 + tid];
            marr[tid]      = m0;
            marr[64 + tid] = m1;
            float mv = m0 + m1;
            for (int off = 32; off > 0; off >>= 1)
                mv += __shfl_xor(mv, off);
            if (tid == 0) msum = mv;
        }
        __syncthreads();

        const f32x4* eb = (const f32x4*)emb + (size_t)bs * Lq * D4 + tid;
        f32x4 acc = {0.f, 0.f, 0.f, 0.f};
#pragma unroll 16
        for (int l = 0; l < Lq; ++l) {
            float m = marr[l];                   // LDS broadcast
            f32x4 v = eb[(size_t)l * D4];        // coalesced, seeds L2
            acc += v * m;
        }
        float inv = 1.0f / fmaxf(msum, 1.0f);    // clip(count, 1, None)
        f32x4 r = acc * inv;
        __builtin_nontemporal_store(r, (f32x4*)out + (size_t)bs * D4 + tid);
        return;
    }

    // ---- arg embeddings: block = (b,s); wave = set; loop a = 0..9 --------
    int bs   = bid - NPOOL;
    int set  = tid >> 6;               // wave index = set (0:pred 1:a0 2:a1)
    int lane = tid & 63;
    const int* ids = (set == 0) ? pred : ((set == 1) ? a0 : a1);

    // whole sentence in 2 regs/lane; no LDS, no barriers
    int s0 = sids[(size_t)bs * Lq + lane];
    int s1 = sids[(size_t)bs * Lq + 64 + lane];

    const f32x4* eb = (const f32x4*)emb + (size_t)bs * Lq * D4;

    for (int a = 0; a < Aq; ++a) {
        int bsa = bs * Aq + a;
        int idv = (lane < Tq) ? ids[(size_t)bsa * Tq + lane] : 0;

        // last t (descending) whose nonzero id occurs in the sentence
        unsigned long long B0 = 0, B1 = 0;
        int ccount = 0;
#pragma unroll
        for (int t = Tq - 1; t >= 0; --t) {
            if (ccount == 0) {                       // wave-uniform
                int idt = __shfl(idv, t);
                if (idt != 0) {
                    unsigned long long b0 = __ballot(s0 == idt);
                    unsigned long long b1 = __ballot(s1 == idt);
                    int c = (int)(__popcll(b0) + __popcll(b1));
                    if (c > 0) { B0 = b0; B1 = b1; ccount = c; }
                }
            }
        }

        // gather matched rows (uniform bit loops, ascending l: deterministic)
        f32x4 acc0 = {0.f, 0.f, 0.f, 0.f};
        f32x4 acc1 = acc0, acc2 = acc0;
        unsigned long long b = B0;
        while (b) {
            int l = (int)__builtin_ctzll(b); b &= b - 1;
            acc0 += eb[(size_t)l * D4 + lane];
            acc1 += eb[(size_t)l * D4 + 64 + lane];
            acc2 += eb[(size_t)l * D4 + 128 + lane];
        }
        b = B1;
        while (b) {
            int l = (int)__builtin_ctzll(b) + 64; b &= b - 1;
            acc0 += eb[(size_t)l * D4 + lane];
            acc1 += eb[(size_t)l * D4 + 64 + lane];
            acc2 += eb[(size_t)l * D4 + 128 + lane];
        }

        float inv = (ccount > 0) ? 1.0f / (float)ccount : 0.0f;
        f32x4* o4 = (f32x4*)out +
                    ((size_t)NBS + (size_t)set * NBSA + bsa) * D4;
        __builtin_nontemporal_store(acc0 * inv, o4 + lane);
        __builtin_nontemporal_store(acc1 * inv, o4 + 64 + lane);
        __builtin_nontemporal_store(acc2 * inv, o4 + 128 + lane);
    }
}

extern "C" void kernel_launch(void* const* d_in, const int* in_sizes, int n_in,
                              void* d_out, int out_size, void* d_ws, size_t ws_size,
                              hipStream_t stream) {
    const int*   sids = (const int*)d_in[0];
    const float* mask = (const float*)d_in[1];
    const float* emb  = (const float*)d_in[2];
    const int*   pred = (const int*)d_in[3];
    const int*   a0   = (const int*)d_in[4];
    const int*   a1   = (const int*)d_in[5];
    float* out = (float*)d_out;

    srl_fused_k<<<NPOOL + NARG, 192, 0, stream>>>(sids, mask, emb,
                                                  pred, a0, a1, out);
}